// Round 3
// baseline (364.512 us; speedup 1.0000x reference)
//
#include <hip/hip_runtime.h>

#define NN 4096
#define CC 32
#define TT 12
#define BB 4
#define BT 48          // BB*TT
#define NC 1536        // BT*CC
#define MAXD 192       // mean degree ~82, P(deg>192) astronomically small
#define FW 256         // features per chunk = 8 bt * 32 c; chunk slice = 4096*512B = 2MB, L2-resident
#define NCH 6          // NC / FW

typedef float f32x4 __attribute__((ext_vector_type(4)));
typedef short short8 __attribute__((ext_vector_type(8)));

__device__ __forceinline__ float bf2f(unsigned short h) {
  return __uint_as_float(((unsigned int)h) << 16);
}
__device__ __forceinline__ unsigned short f2bf(float f) {
  unsigned int u = __float_as_uint(f);
  return (unsigned short)((u + 0x7FFFu + ((u >> 16) & 1u)) >> 16);  // RNE
}
__device__ __forceinline__ float blo(unsigned int w) { return __uint_as_float(w << 16); }
__device__ __forceinline__ float bhi(unsigned int w) { return __uint_as_float(w & 0xFFFF0000u); }

// ---- dtype sniffing (bf16 halfwords have plausible exponents)
__global__ void k_detect(const unsigned int* __restrict__ w, int* __restrict__ flag) {
  __shared__ int s;
  if (threadIdx.x == 0) s = 0;
  __syncthreads();
  int h = 0;
  for (int i = threadIdx.x; i < 256; i += 64) {
    unsigned int e = (w[i] >> 7) & 0xFFu;
    if (e >= 90u && e <= 141u) ++h;
  }
  atomicAdd(&s, h);
  __syncthreads();
  if (threadIdx.x == 0) *flag = (s >= 150) ? 1 : 0;
}

// ---- per-row adjacency compaction into edges[].x + degree + d^-1/2
template<int BF16>
__global__ __launch_bounds__(256) void k_build(const void* __restrict__ adjv,
                                               uint2* __restrict__ edges,
                                               int* __restrict__ deg, float* __restrict__ dis,
                                               const int* __restrict__ flag) {
  if ((*flag != 0) != (BF16 != 0)) return;
  __shared__ int cnt;
  int m = blockIdx.x;
  if (threadIdx.x == 0) cnt = 0;
  __syncthreads();
  unsigned int* ecol = (unsigned int*)(edges + m * MAXD);
  if (BF16) {
    const uint4* row = (const uint4*)((const unsigned short*)adjv + (size_t)m * NN);
    for (int i = threadIdx.x; i < NN / 8; i += 256) {
      uint4 v = row[i];
      unsigned int ws[4] = {v.x, v.y, v.z, v.w};
      #pragma unroll
      for (int k = 0; k < 4; ++k) {
        if (ws[k] & 0xFFFFu) {
          int p = atomicAdd(&cnt, 1);
          if (p < MAXD) ecol[p * 2] = (unsigned int)(i * 8 + k * 2);
        }
        if (ws[k] >> 16) {
          int p = atomicAdd(&cnt, 1);
          if (p < MAXD) ecol[p * 2] = (unsigned int)(i * 8 + k * 2 + 1);
        }
      }
    }
  } else {
    const uint4* row = (const uint4*)((const float*)adjv + (size_t)m * NN);
    for (int i = threadIdx.x; i < NN / 4; i += 256) {
      uint4 v = row[i];
      unsigned int ws[4] = {v.x, v.y, v.z, v.w};
      #pragma unroll
      for (int k = 0; k < 4; ++k) {
        if (ws[k] != 0) {
          int p = atomicAdd(&cnt, 1);
          if (p < MAXD) ecol[p * 2] = (unsigned int)(i * 4 + k);
        }
      }
    }
  }
  __syncthreads();
  if (threadIdx.x == 0) {
    int d = cnt < MAXD ? cnt : MAXD;
    deg[m] = d;
    dis[m] = d > 0 ? (float)(1.0 / sqrt((double)d)) : 0.0f;
  }
}

// ---- fill edges[].y = dis[col]  (after all rows' degrees known)
__global__ __launch_bounds__(192) void k_wt(uint2* __restrict__ edges,
                                            const int* __restrict__ deg,
                                            const float* __restrict__ dis) {
  int m = blockIdx.x;
  int j = threadIdx.x;
  if (j < deg[m]) {
    unsigned int* e = (unsigned int*)(edges + m * MAXD + j);
    unsigned int col = e[0];
    e[1] = __float_as_uint(dis[col]);
  }
}

// ---- x[b][c][n][t] -> H[n][bt][c] (bf16), coalesced 8B writes
template<int BF16>
__global__ __launch_bounds__(256) void k_trans(const void* __restrict__ xv,
                                               unsigned short* __restrict__ H,
                                               const int* __restrict__ flag) {
  if ((*flag != 0) != (BF16 != 0)) return;
  int i = blockIdx.x * 256 + threadIdx.x;   // i < NN*BT*8
  int c4 = (i & 7) << 2;
  int r  = i >> 3;            // r = n*BT + bt
  int bt = r % BT;
  int b  = bt / TT;
  int t  = bt - b * TT;
  int n  = r / BT;
  const size_t S = (size_t)NN * TT;
  size_t src = ((((size_t)b * CC + c4) * NN + n) * TT + t);
  ushort4 v;
  if (BF16) {
    const unsigned short* x = (const unsigned short*)xv;
    v.x = x[src]; v.y = x[src + S]; v.z = x[src + 2 * S]; v.w = x[src + 3 * S];
  } else {
    const float* x = (const float*)xv;
    v.x = f2bf(x[src]); v.y = f2bf(x[src + S]);
    v.z = f2bf(x[src + 2 * S]); v.w = f2bf(x[src + 3 * S]);
  }
  *(ushort4*)(H + (size_t)r * CC + c4) = v;
}

// ---- pure gather: T1[m] = H[m] - dis[m] * sum_e dis[col]*H[col]
// block = 384 = 6 waves; m = blockIdx.x (wave-uniform edge stream -> s_loads),
// wave wid handles feature chunk wid. Zero LDS.
__global__ __launch_bounds__(384) void k_gather1(const unsigned short* __restrict__ H,
                                                 const uint2* __restrict__ edges,
                                                 const int* __restrict__ deg,
                                                 const float* __restrict__ dis,
                                                 unsigned short* __restrict__ T1) {
  int m = blockIdx.x;
  int wid = threadIdx.x >> 6, lane = threadIdx.x & 63;
  int d = deg[m];
  float dm = dis[m];
  const uint2* ep = edges + m * MAXD;
  int fo = wid * FW + (lane << 2);
  const unsigned short* Hf = H + fo;
  float a0 = 0.f, a1 = 0.f, a2 = 0.f, a3 = 0.f;
  #pragma unroll 4
  for (int e = 0; e < d; ++e) {
    uint2 ew = ep[e];                 // uniform -> s_load_dwordx2 (batched)
    int cc = (int)ew.x;
    float w = __uint_as_float(ew.y);
    uint2 hv = *(const uint2*)(Hf + cc * NC);
    a0 = fmaf(w, blo(hv.x), a0);
    a1 = fmaf(w, bhi(hv.x), a1);
    a2 = fmaf(w, blo(hv.y), a2);
    a3 = fmaf(w, bhi(hv.y), a3);
  }
  uint2 hm = *(const uint2*)(Hf + m * NC);
  ushort4 o;
  o.x = f2bf(blo(hm.x) - dm * a0);
  o.y = f2bf(bhi(hm.x) - dm * a1);
  o.z = f2bf(blo(hm.y) - dm * a2);
  o.w = f2bf(bhi(hm.y) - dm * a3);
  *(ushort4*)(T1 + (size_t)m * NC + fo) = o;
}

// ---- pure gather: T2[m] = 2*T1[m] - 2*dm*sum_e dis[col]*T1[col] - H[m]
__global__ __launch_bounds__(384) void k_gather2(const unsigned short* __restrict__ H,
                                                 const unsigned short* __restrict__ T1,
                                                 const uint2* __restrict__ edges,
                                                 const int* __restrict__ deg,
                                                 const float* __restrict__ dis,
                                                 unsigned short* __restrict__ T2) {
  int m = blockIdx.x;
  int wid = threadIdx.x >> 6, lane = threadIdx.x & 63;
  int d = deg[m];
  float dm = dis[m];
  const uint2* ep = edges + m * MAXD;
  int fo = wid * FW + (lane << 2);
  const unsigned short* Tf = T1 + fo;
  float a0 = 0.f, a1 = 0.f, a2 = 0.f, a3 = 0.f;
  #pragma unroll 4
  for (int e = 0; e < d; ++e) {
    uint2 ew = ep[e];
    int cc = (int)ew.x;
    float w = __uint_as_float(ew.y);
    uint2 hv = *(const uint2*)(Tf + cc * NC);
    a0 = fmaf(w, blo(hv.x), a0);
    a1 = fmaf(w, bhi(hv.x), a1);
    a2 = fmaf(w, blo(hv.y), a2);
    a3 = fmaf(w, bhi(hv.y), a3);
  }
  uint2 tm = *(const uint2*)(Tf + m * NC);
  uint2 hm = *(const uint2*)(H + (size_t)m * NC + fo);
  float td = 2.f * dm;
  ushort4 o;
  o.x = f2bf(2.f * blo(tm.x) - td * a0 - blo(hm.x));
  o.y = f2bf(2.f * bhi(tm.x) - td * a1 - bhi(hm.x));
  o.z = f2bf(2.f * blo(tm.y) - td * a2 - blo(hm.y));
  o.w = f2bf(2.f * bhi(tm.y) - td * a3 - bhi(hm.y));
  *(ushort4*)(T2 + (size_t)m * NC + fo) = o;
}

// ---- MFMA channel mix: out = W0*H + W1*T1 + W2*T2 + bias, store [B,32,N,T]
// GEMM [196608 x 96] x [96 x 32]; 16x16x32 bf16 MFMA; W split hi/lo bf16.
// Wave handles 2 row-tiles of 16; block = 256 (4 waves).
template<int BF16>
__global__ __launch_bounds__(256) void k_mix(const unsigned short* __restrict__ H,
                                             const unsigned short* __restrict__ T1,
                                             const unsigned short* __restrict__ T2,
                                             const void* __restrict__ wgtv,
                                             const void* __restrict__ biasv,
                                             void* __restrict__ outv,
                                             const int* __restrict__ flag) {
  if ((*flag != 0) != (BF16 != 0)) return;
  int wid = threadIdx.x >> 6, lane = threadIdx.x & 63;
  int wgi = blockIdx.x * 4 + wid;     // global wave id
  int lm = lane & 15, quad = lane >> 4;
  // B-frags: B[k=quad*8+j][n=lm] = W[g][c=k][o=h*16+n]
  short8 bhf[2][3], blf[2][3];
  for (int h = 0; h < 2; ++h) {
    for (int g = 0; g < 3; ++g) {
      short8 vh, vl;
      #pragma unroll
      for (int j = 0; j < 8; ++j) {
        int c = quad * 8 + j;
        int o = h * 16 + lm;
        float w = BF16 ? bf2f(((const unsigned short*)wgtv)[(g * CC + c) * CC + o])
                       : ((const float*)wgtv)[(g * CC + c) * CC + o];
        unsigned short hi = f2bf(w);
        float rem = w - bf2f(hi);
        vh[j] = (short)hi;
        vl[j] = (short)f2bf(rem);
      }
      bhf[h][g] = vh;
      blf[h][g] = vl;
    }
  }
  float bias0[2];
  #pragma unroll
  for (int h = 0; h < 2; ++h) {
    bias0[h] = BF16 ? bf2f(((const unsigned short*)biasv)[h * 16 + lm])
                    : ((const float*)biasv)[h * 16 + lm];
  }
  const size_t S = (size_t)NN * TT;
  #pragma unroll
  for (int tI = 0; tI < 2; ++tI) {
    int r0 = (wgi * 2 + tI) * 16;
    size_t abase = (size_t)(r0 + lm) * CC + quad * 8;
    short8 af0 = *(const short8*)(H + abase);
    short8 af1 = *(const short8*)(T1 + abase);
    short8 af2 = *(const short8*)(T2 + abase);
    #pragma unroll
    for (int h = 0; h < 2; ++h) {
      f32x4 acc = {bias0[h], bias0[h], bias0[h], bias0[h]};
      acc = __builtin_amdgcn_mfma_f32_16x16x32_bf16(af0, bhf[h][0], acc, 0, 0, 0);
      acc = __builtin_amdgcn_mfma_f32_16x16x32_bf16(af0, blf[h][0], acc, 0, 0, 0);
      acc = __builtin_amdgcn_mfma_f32_16x16x32_bf16(af1, bhf[h][1], acc, 0, 0, 0);
      acc = __builtin_amdgcn_mfma_f32_16x16x32_bf16(af1, blf[h][1], acc, 0, 0, 0);
      acc = __builtin_amdgcn_mfma_f32_16x16x32_bf16(af2, bhf[h][2], acc, 0, 0, 0);
      acc = __builtin_amdgcn_mfma_f32_16x16x32_bf16(af2, blf[h][2], acc, 0, 0, 0);
      int o = h * 16 + lm;
      #pragma unroll
      for (int reg = 0; reg < 4; ++reg) {
        int r = r0 + quad * 4 + reg;
        int n = r / BT, bt = r - n * BT;
        int b = bt / TT, t = bt - b * TT;
        size_t ob = (((size_t)b * CC + o) * NN + n) * TT + t;
        if (BF16) ((unsigned short*)outv)[ob] = f2bf(acc[reg]);
        else      ((float*)outv)[ob] = acc[reg];
      }
    }
  }
}

extern "C" void kernel_launch(void* const* d_in, const int* in_sizes, int n_in,
                              void* d_out, int out_size, void* d_ws, size_t ws_size,
                              hipStream_t stream) {
  const void* x    = d_in[0];
  const void* adj  = d_in[1];
  const void* wgt  = d_in[2];
  const void* bias = d_in[3];
  char* ws = (char*)d_ws;
  // ws layout (~44.2 MB total):
  int*   flag = (int*)ws;                                   // 256 B
  float* dis  = (float*)(ws + 256);                         // 16 KB
  int*   deg  = (int*)(ws + 256 + 16384);                   // 16 KB
  uint2* edges = (uint2*)(ws + 256 + 32768);                // 4096*192*8 = 6.29 MB
  char* p = ws + 256 + 32768 + (size_t)NN * MAXD * 8;
  unsigned short* H  = (unsigned short*)p;                  // 12.58 MB
  unsigned short* T1 = (unsigned short*)(p + (size_t)NN * NC * 2);
  unsigned short* T2 = (unsigned short*)(p + (size_t)NN * NC * 4);

  k_detect<<<1, 64, 0, stream>>>((const unsigned int*)wgt, flag);
  k_build<1><<<NN, 256, 0, stream>>>(adj, edges, deg, dis, flag);
  k_build<0><<<NN, 256, 0, stream>>>(adj, edges, deg, dis, flag);
  k_wt<<<NN, 192, 0, stream>>>(edges, deg, dis);
  k_trans<1><<<(NN * BT * 8) / 256, 256, 0, stream>>>(x, H, flag);
  k_trans<0><<<(NN * BT * 8) / 256, 256, 0, stream>>>(x, H, flag);
  k_gather1<<<NN, 384, 0, stream>>>(H, edges, deg, dis, T1);
  k_gather2<<<NN, 384, 0, stream>>>(H, T1, edges, deg, dis, T2);
  k_mix<1><<<(NN * BT) / (16 * 2 * 4), 256, 0, stream>>>(H, T1, T2, wgt, bias, d_out, flag);
  k_mix<0><<<(NN * BT) / (16 * 2 * 4), 256, 0, stream>>>(H, T1, T2, wgt, bias, d_out, flag);
}

// Round 4
// 285.885 us; speedup vs baseline: 1.2750x; 1.2750x over previous
//
#include <hip/hip_runtime.h>

#define NN 4096
#define CC 32
#define TT 12
#define BB 4
#define BT 48          // BB*TT
#define NC 1536        // BT*CC
#define MAXD 192       // mean degree ~82, P(deg>192) astronomically small
#define FW 256         // features per chunk = 8 bt * 32 c; chunk slice = 4096*512B = 2MB, L2-resident
#define NCH 6          // NC / FW
#define SOP 33         // sOut padded row stride (floats) in k_mix

typedef float f32x4 __attribute__((ext_vector_type(4)));
typedef short short8 __attribute__((ext_vector_type(8)));

__device__ __forceinline__ float bf2f(unsigned short h) {
  return __uint_as_float(((unsigned int)h) << 16);
}
__device__ __forceinline__ unsigned short f2bf(float f) {
  unsigned int u = __float_as_uint(f);
  return (unsigned short)((u + 0x7FFFu + ((u >> 16) & 1u)) >> 16);  // RNE
}
__device__ __forceinline__ float blo(unsigned int w) { return __uint_as_float(w << 16); }
__device__ __forceinline__ float bhi(unsigned int w) { return __uint_as_float(w & 0xFFFF0000u); }

// ---- dtype sniffing (bf16 halfwords have plausible exponents)
__global__ void k_detect(const unsigned int* __restrict__ w, int* __restrict__ flag) {
  __shared__ int s;
  if (threadIdx.x == 0) s = 0;
  __syncthreads();
  int h = 0;
  for (int i = threadIdx.x; i < 256; i += 64) {
    unsigned int e = (w[i] >> 7) & 0xFFu;
    if (e >= 90u && e <= 141u) ++h;
  }
  atomicAdd(&s, h);
  __syncthreads();
  if (threadIdx.x == 0) *flag = (s >= 150) ? 1 : 0;
}

// ---- per-row adjacency compaction into edges[].x + degree + d^-1/2
template<int BF16>
__global__ __launch_bounds__(256) void k_build(const void* __restrict__ adjv,
                                               uint2* __restrict__ edges,
                                               int* __restrict__ deg, float* __restrict__ dis,
                                               const int* __restrict__ flag) {
  if ((*flag != 0) != (BF16 != 0)) return;
  __shared__ int cnt;
  int m = blockIdx.x;
  if (threadIdx.x == 0) cnt = 0;
  __syncthreads();
  unsigned int* ecol = (unsigned int*)(edges + m * MAXD);
  if (BF16) {
    const uint4* row = (const uint4*)((const unsigned short*)adjv + (size_t)m * NN);
    for (int i = threadIdx.x; i < NN / 8; i += 256) {
      uint4 v = row[i];
      unsigned int ws[4] = {v.x, v.y, v.z, v.w};
      #pragma unroll
      for (int k = 0; k < 4; ++k) {
        if (ws[k] & 0xFFFFu) {
          int p = atomicAdd(&cnt, 1);
          if (p < MAXD) ecol[p * 2] = (unsigned int)(i * 8 + k * 2);
        }
        if (ws[k] >> 16) {
          int p = atomicAdd(&cnt, 1);
          if (p < MAXD) ecol[p * 2] = (unsigned int)(i * 8 + k * 2 + 1);
        }
      }
    }
  } else {
    const uint4* row = (const uint4*)((const float*)adjv + (size_t)m * NN);
    for (int i = threadIdx.x; i < NN / 4; i += 256) {
      uint4 v = row[i];
      unsigned int ws[4] = {v.x, v.y, v.z, v.w};
      #pragma unroll
      for (int k = 0; k < 4; ++k) {
        if (ws[k] != 0) {
          int p = atomicAdd(&cnt, 1);
          if (p < MAXD) ecol[p * 2] = (unsigned int)(i * 4 + k);
        }
      }
    }
  }
  __syncthreads();
  if (threadIdx.x == 0) {
    int d = cnt < MAXD ? cnt : MAXD;
    deg[m] = d;
    dis[m] = d > 0 ? (float)(1.0 / sqrt((double)d)) : 0.0f;
  }
}

// ---- fill edges[].y = dis[col]
__global__ __launch_bounds__(192) void k_wt(uint2* __restrict__ edges,
                                            const int* __restrict__ deg,
                                            const float* __restrict__ dis) {
  int m = blockIdx.x;
  int j = threadIdx.x;
  if (j < deg[m]) {
    unsigned int* e = (unsigned int*)(edges + m * MAXD + j);
    unsigned int col = e[0];
    e[1] = __float_as_uint(dis[col]);
  }
}

// ---- x[b][c][n][t] -> H[n][bt][c] (bf16), coalesced 8B writes
template<int BF16>
__global__ __launch_bounds__(256) void k_trans(const void* __restrict__ xv,
                                               unsigned short* __restrict__ H,
                                               const int* __restrict__ flag) {
  if ((*flag != 0) != (BF16 != 0)) return;
  int i = blockIdx.x * 256 + threadIdx.x;   // i < NN*BT*8
  int c4 = (i & 7) << 2;
  int r  = i >> 3;            // r = n*BT + bt
  int bt = r % BT;
  int b  = bt / TT;
  int t  = bt - b * TT;
  int n  = r / BT;
  const size_t S = (size_t)NN * TT;
  size_t src = ((((size_t)b * CC + c4) * NN + n) * TT + t);
  ushort4 v;
  if (BF16) {
    const unsigned short* x = (const unsigned short*)xv;
    v.x = x[src]; v.y = x[src + S]; v.z = x[src + 2 * S]; v.w = x[src + 3 * S];
  } else {
    const float* x = (const float*)xv;
    v.x = f2bf(x[src]); v.y = f2bf(x[src + S]);
    v.z = f2bf(x[src + 2 * S]); v.w = f2bf(x[src + 3 * S]);
  }
  *(ushort4*)(H + (size_t)r * CC + c4) = v;
}

// ---- chunked + scalarized gather: T1[m,q] = H[m,q] - dis[m]*sum_e dis[col]*H[col,q]
// grid (NN/4, NCH), block 256 = 4 waves. Wave wid owns node bx*4+wid, chunk by.
// readfirstlane keeps the edge stream provably wave-uniform -> s_load batching.
__global__ __launch_bounds__(256) void k_gather1(const unsigned short* __restrict__ H,
                                                 const uint2* __restrict__ edges,
                                                 const int* __restrict__ deg,
                                                 const float* __restrict__ dis,
                                                 unsigned short* __restrict__ T1) {
  int wid = __builtin_amdgcn_readfirstlane(threadIdx.x >> 6);
  int lane = threadIdx.x & 63;
  int m = blockIdx.x * 4 + wid;
  int q = blockIdx.y;
  int d = deg[m];
  float dm = dis[m];
  const uint2* ep = edges + m * MAXD;
  int fo = q * FW + (lane << 2);
  const unsigned short* Hf = H + fo;
  float a0 = 0.f, a1 = 0.f, a2 = 0.f, a3 = 0.f;
  #pragma unroll 4
  for (int e = 0; e < d; ++e) {
    uint2 ew = ep[e];                 // uniform -> s_load_dwordx2 (batched)
    int cc = (int)ew.x;
    float w = __uint_as_float(ew.y);
    uint2 hv = *(const uint2*)(Hf + cc * NC);
    a0 = fmaf(w, blo(hv.x), a0);
    a1 = fmaf(w, bhi(hv.x), a1);
    a2 = fmaf(w, blo(hv.y), a2);
    a3 = fmaf(w, bhi(hv.y), a3);
  }
  uint2 hm = *(const uint2*)(Hf + m * NC);
  ushort4 o;
  o.x = f2bf(blo(hm.x) - dm * a0);
  o.y = f2bf(bhi(hm.x) - dm * a1);
  o.z = f2bf(blo(hm.y) - dm * a2);
  o.w = f2bf(bhi(hm.y) - dm * a3);
  *(ushort4*)(T1 + (size_t)m * NC + fo) = o;
}

// ---- chunked + scalarized: T2[m,q] = 2*T1[m,q] - 2*dm*sum_e dis[col]*T1[col,q] - H[m,q]
__global__ __launch_bounds__(256) void k_gather2(const unsigned short* __restrict__ H,
                                                 const unsigned short* __restrict__ T1,
                                                 const uint2* __restrict__ edges,
                                                 const int* __restrict__ deg,
                                                 const float* __restrict__ dis,
                                                 unsigned short* __restrict__ T2) {
  int wid = __builtin_amdgcn_readfirstlane(threadIdx.x >> 6);
  int lane = threadIdx.x & 63;
  int m = blockIdx.x * 4 + wid;
  int q = blockIdx.y;
  int d = deg[m];
  float dm = dis[m];
  const uint2* ep = edges + m * MAXD;
  int fo = q * FW + (lane << 2);
  const unsigned short* Tf = T1 + fo;
  float a0 = 0.f, a1 = 0.f, a2 = 0.f, a3 = 0.f;
  #pragma unroll 4
  for (int e = 0; e < d; ++e) {
    uint2 ew = ep[e];
    int cc = (int)ew.x;
    float w = __uint_as_float(ew.y);
    uint2 hv = *(const uint2*)(Tf + cc * NC);
    a0 = fmaf(w, blo(hv.x), a0);
    a1 = fmaf(w, bhi(hv.x), a1);
    a2 = fmaf(w, blo(hv.y), a2);
    a3 = fmaf(w, bhi(hv.y), a3);
  }
  uint2 tm = *(const uint2*)(Tf + m * NC);
  uint2 hm = *(const uint2*)(H + (size_t)m * NC + fo);
  float td = 2.f * dm;
  ushort4 o;
  o.x = f2bf(2.f * blo(tm.x) - td * a0 - blo(hm.x));
  o.y = f2bf(2.f * bhi(tm.x) - td * a1 - bhi(hm.x));
  o.z = f2bf(2.f * blo(tm.y) - td * a2 - blo(hm.y));
  o.w = f2bf(2.f * bhi(tm.y) - td * a3 - bhi(hm.y));
  *(ushort4*)(T2 + (size_t)m * NC + fo) = o;
}

// ---- MFMA channel mix with LDS-transposed COALESCED stores.
// Block = 4 nodes (192 rows x 32 outs); wave wid MFMAs node wid (3 tiles x 2 halves),
// C-frags -> padded LDS, barrier, threads store contiguous (b,o) runs of 48 elems.
template<int BF16>
__global__ __launch_bounds__(256) void k_mix(const unsigned short* __restrict__ H,
                                             const unsigned short* __restrict__ T1,
                                             const unsigned short* __restrict__ T2,
                                             const void* __restrict__ wgtv,
                                             const void* __restrict__ biasv,
                                             void* __restrict__ outv,
                                             const int* __restrict__ flag) {
  if ((*flag != 0) != (BF16 != 0)) return;
  __shared__ __align__(16) float sOut[192 * SOP];
  int wid = threadIdx.x >> 6, lane = threadIdx.x & 63;
  int lm = lane & 15, quad = lane >> 4;
  // B-frags: B[k=quad*8+j][n=lm] = W[g][c=k][o=h*16+lm], hi/lo bf16 split
  short8 bhf[2][3], blf[2][3];
  for (int h = 0; h < 2; ++h) {
    for (int g = 0; g < 3; ++g) {
      short8 vh, vl;
      #pragma unroll
      for (int j = 0; j < 8; ++j) {
        int c = quad * 8 + j;
        int o = h * 16 + lm;
        float w = BF16 ? bf2f(((const unsigned short*)wgtv)[(g * CC + c) * CC + o])
                       : ((const float*)wgtv)[(g * CC + c) * CC + o];
        unsigned short hi = f2bf(w);
        float rem = w - bf2f(hi);
        vh[j] = (short)hi;
        vl[j] = (short)f2bf(rem);
      }
      bhf[h][g] = vh;
      blf[h][g] = vl;
    }
  }
  float bias0[2];
  #pragma unroll
  for (int h = 0; h < 2; ++h) {
    bias0[h] = BF16 ? bf2f(((const unsigned short*)biasv)[h * 16 + lm])
                    : ((const float*)biasv)[h * 16 + lm];
  }
  int n0 = blockIdx.x * 4;                  // first node of this block
  #pragma unroll
  for (int tI = 0; tI < 3; ++tI) {
    int r0l = wid * BT + tI * 16;           // local row (within 192)
    size_t abase = ((size_t)(n0 * BT) + r0l + lm) * CC + quad * 8;
    short8 af0 = *(const short8*)(H + abase);
    short8 af1 = *(const short8*)(T1 + abase);
    short8 af2 = *(const short8*)(T2 + abase);
    #pragma unroll
    for (int h = 0; h < 2; ++h) {
      f32x4 acc = {bias0[h], bias0[h], bias0[h], bias0[h]};
      acc = __builtin_amdgcn_mfma_f32_16x16x32_bf16(af0, bhf[h][0], acc, 0, 0, 0);
      acc = __builtin_amdgcn_mfma_f32_16x16x32_bf16(af0, blf[h][0], acc, 0, 0, 0);
      acc = __builtin_amdgcn_mfma_f32_16x16x32_bf16(af1, bhf[h][1], acc, 0, 0, 0);
      acc = __builtin_amdgcn_mfma_f32_16x16x32_bf16(af1, blf[h][1], acc, 0, 0, 0);
      acc = __builtin_amdgcn_mfma_f32_16x16x32_bf16(af2, bhf[h][2], acc, 0, 0, 0);
      acc = __builtin_amdgcn_mfma_f32_16x16x32_bf16(af2, blf[h][2], acc, 0, 0, 0);
      int o = h * 16 + lm;
      #pragma unroll
      for (int reg = 0; reg < 4; ++reg) {
        sOut[(r0l + quad * 4 + reg) * SOP + o] = acc[reg];
      }
    }
  }
  __syncthreads();
  // store: 128 (b,o) pairs x 48 contiguous elems; 1536 vec4 chunks, 6 per thread
  #pragma unroll
  for (int j = 0; j < 6; ++j) {
    int idx = j * 256 + threadIdx.x;
    int bo = idx / 12;                      // = b*32 + o
    int fq = idx - bo * 12;
    int b = bo >> 5, o = bo & 31;
    int p0 = fq * 4;                        // element within the 48-run
    float v[4];
    #pragma unroll
    for (int k = 0; k < 4; ++k) {
      int p = p0 + k;
      int nl = p / 12, t = p - nl * 12;
      v[k] = sOut[(nl * BT + b * TT + t) * SOP + o];
    }
    size_t base = (((size_t)bo * NN) + n0) * TT + p0;
    if (BF16) {
      ushort4 s = {f2bf(v[0]), f2bf(v[1]), f2bf(v[2]), f2bf(v[3])};
      *(ushort4*)((unsigned short*)outv + base) = s;
    } else {
      *(float4*)((float*)outv + base) = make_float4(v[0], v[1], v[2], v[3]);
    }
  }
}

extern "C" void kernel_launch(void* const* d_in, const int* in_sizes, int n_in,
                              void* d_out, int out_size, void* d_ws, size_t ws_size,
                              hipStream_t stream) {
  const void* x    = d_in[0];
  const void* adj  = d_in[1];
  const void* wgt  = d_in[2];
  const void* bias = d_in[3];
  char* ws = (char*)d_ws;
  int*   flag = (int*)ws;                                   // 256 B
  float* dis  = (float*)(ws + 256);                         // 16 KB
  int*   deg  = (int*)(ws + 256 + 16384);                   // 16 KB
  uint2* edges = (uint2*)(ws + 256 + 32768);                // 6.29 MB
  char* p = ws + 256 + 32768 + (size_t)NN * MAXD * 8;
  unsigned short* H  = (unsigned short*)p;                  // 12.58 MB
  unsigned short* T1 = (unsigned short*)(p + (size_t)NN * NC * 2);
  unsigned short* T2 = (unsigned short*)(p + (size_t)NN * NC * 4);

  k_detect<<<1, 64, 0, stream>>>((const unsigned int*)wgt, flag);
  k_build<1><<<NN, 256, 0, stream>>>(adj, edges, deg, dis, flag);
  k_build<0><<<NN, 256, 0, stream>>>(adj, edges, deg, dis, flag);
  k_wt<<<NN, 192, 0, stream>>>(edges, deg, dis);
  k_trans<1><<<(NN * BT * 8) / 256, 256, 0, stream>>>(x, H, flag);
  k_trans<0><<<(NN * BT * 8) / 256, 256, 0, stream>>>(x, H, flag);
  k_gather1<<<dim3(NN / 4, NCH), 256, 0, stream>>>(H, edges, deg, dis, T1);
  k_gather2<<<dim3(NN / 4, NCH), 256, 0, stream>>>(H, T1, edges, deg, dis, T2);
  k_mix<1><<<NN / 4, 256, 0, stream>>>(H, T1, T2, wgt, bias, d_out, flag);
  k_mix<0><<<NN / 4, 256, 0, stream>>>(H, T1, T2, wgt, bias, d_out, flag);
}